// Round 3
// baseline (438.084 us; speedup 1.0000x reference)
//
#include <hip/hip_runtime.h>

// LSTM B=4096, T=512, I=1, H=64, O=1 (fp32 in/out).
// Round 3: grid=512, MB=8 batches/block (2 blocks/CU -> 2 chains/SIMD for
// latency overlap), h stored in LDS as f16 hi/lo (split at write, read as
// MFMA-ready b128 fragments), ping-pong h buffers -> ONE barrier per step.
// Gates = h @ W_hh^T via mfma_f32_16x16x32_f16, hi/lo split in K:
//   gates = h_hi@W16 + h_lo@W16   (h split exact; W fp16-rounded once)
// Wave w owns N-tiles {w,w+4,w+8,w+12} (gate groups s=0..3 at n=64s+16w+l16)
// -> all 4 gates of cell (m, j=16w+l16) colocate in one lane (m=h0*4+r).
// MB=8 => only acc rows m<8 valid (lanes h0<2); redistribute r{2,3} to the
// upper half-wave via shfl_xor(32) so every lane activates 2 cells.
// MFMA layouts (m89/m120-verified): A[m=lane&15][k=(lane>>4)*8+i],
// B[k=(lane>>4)*8+i][n=lane&15], D[m=(lane>>4)*4+r][n=lane&15].

#define TT   512
#define MB   8
#define HPAD 72            // f16 row stride: 2-way bank alias max (free)
#define HALF (16 * HPAD)   // offset of lo plane within a buffer
#define BUFH (2 * HALF)    // one ping-pong buffer (hi+lo planes)
#define SXP  9             // sh_x row stride (floats): conflict-free staging

typedef _Float16 f16x8 __attribute__((ext_vector_type(8)));
typedef float    f32x4 __attribute__((ext_vector_type(4)));

#define MFMA16(a, b, c) __builtin_amdgcn_mfma_f32_16x16x32_f16((a), (b), (c), 0, 0, 0)

__device__ __forceinline__ float rcp_(float x) { return __builtin_amdgcn_rcpf(x); }
__device__ __forceinline__ float sigmoid_(float x) { return rcp_(1.0f + __expf(-x)); }
__device__ __forceinline__ float tanh_(float x) { return 1.0f - 2.0f * rcp_(1.0f + __expf(2.0f * x)); }

__device__ __forceinline__ f16x8 cvt8(const float4& u0, const float4& u1) {
    f16x8 r;
    r[0] = (_Float16)u0.x; r[1] = (_Float16)u0.y; r[2] = (_Float16)u0.z; r[3] = (_Float16)u0.w;
    r[4] = (_Float16)u1.x; r[5] = (_Float16)u1.y; r[6] = (_Float16)u1.z; r[7] = (_Float16)u1.w;
    return r;
}

__global__ __launch_bounds__(256, 2) void lstm_mfma(
    const float* __restrict__ x,      // [4096, 512]
    const float* __restrict__ w_ih,   // [256]
    const float* __restrict__ w_hh,   // [256, 64]
    const float* __restrict__ b_ih,   // [256]
    const float* __restrict__ b_hh,   // [256]
    const float* __restrict__ w_out,  // [64]
    const float* __restrict__ b_out,  // [1]
    float* __restrict__ out)          // [4096]
{
    __shared__ __align__(16) float     sh_x[TT * SXP];   // [t][m] padded, 18 KB
    __shared__ __align__(16) _Float16  hbuf[2 * BUFH];   // 2 bufs x (hi,lo) x 16 x HPAD, 9 KB

    const int tid = threadIdx.x;
    const int w   = tid >> 6;    // wave 0..3
    const int L   = tid & 63;
    const int l16 = L & 15;
    const int h0  = L >> 4;      // 0..3
    const int b0  = blockIdx.x * MB;
    const int j   = 16 * w + l16;  // hidden unit owned by this lane

    // ---- stage x: sh_x[t*SXP + m] = x[b0+m][t] (conflict-free, coalesced) ----
    {
        const int q = tid >> 5;   // batch 0..7
        const int l = tid & 31;
        const float* xr = x + (size_t)(b0 + q) * TT;
        #pragma unroll
        for (int i = 0; i < TT / 32; ++i)
            sh_x[(l + 32 * i) * SXP + q] = xr[l + 32 * i];
    }
    // ---- zero both h buffers (rows 8..15 stay zero forever) ----
    for (int i = tid; i < 2 * BUFH; i += 256) hbuf[i] = (_Float16)0.0f;

    // ---- preload W_hh fragments (fp16-rounded once) ----
    f16x8 Bf[4][2];
    float wihv[4], biasv[4];
    #pragma unroll
    for (int s = 0; s < 4; ++s) {
        const int n = 64 * s + j;
        #pragma unroll
        for (int kt = 0; kt < 2; ++kt) {
            const float* p = w_hh + n * 64 + kt * 32 + h0 * 8;
            float4 u0 = *(const float4*)p;
            float4 u1 = *(const float4*)(p + 4);
            Bf[s][kt] = cvt8(u0, u1);
        }
        wihv[s]  = w_ih[n];
        biasv[s] = b_ih[n] + b_hh[n];
    }

    // lane's 2 cells: m0, m0+1 (h0<2 -> r{0,1} of row-block h0&1; h0>=2 -> r{2,3})
    const int  m0    = (h0 & 1) * 4 + ((h0 < 2) ? 0 : 2);
    const bool lohalf = (h0 < 2);
    const int  aoff  = l16 * HPAD + h0 * 8;   // A-fragment LDS offset (f16 units)
    const int  woff0 = m0 * HPAD + j;         // h-write offsets
    const int  woff1 = (m0 + 1) * HPAD + j;

    float cc0 = 0.0f, cc1 = 0.0f;
    __syncthreads();

    for (int t = 0; t < TT; ++t) {
        const int cur = t & 1;
        const _Float16* rb = hbuf + cur * BUFH;
        _Float16*       wb = hbuf + (cur ^ 1) * BUFH;

        // ---- A fragments: direct f16 b128 reads (hi/lo x 2 K-tiles) ----
        f16x8 ah0 = *(const f16x8*)(rb + aoff);
        f16x8 ah1 = *(const f16x8*)(rb + aoff + 32);
        f16x8 al0 = *(const f16x8*)(rb + HALF + aoff);
        f16x8 al1 = *(const f16x8*)(rb + HALF + aoff + 32);

        f32x4 a0 = {0.f, 0.f, 0.f, 0.f};
        f32x4 a1 = {0.f, 0.f, 0.f, 0.f};
        f32x4 a2 = {0.f, 0.f, 0.f, 0.f};
        f32x4 a3 = {0.f, 0.f, 0.f, 0.f};
        a0 = MFMA16(ah0, Bf[0][0], a0);
        a1 = MFMA16(ah0, Bf[1][0], a1);
        a2 = MFMA16(ah0, Bf[2][0], a2);
        a3 = MFMA16(ah0, Bf[3][0], a3);
        a0 = MFMA16(ah1, Bf[0][1], a0);
        a1 = MFMA16(ah1, Bf[1][1], a1);
        a2 = MFMA16(ah1, Bf[2][1], a2);
        a3 = MFMA16(ah1, Bf[3][1], a3);
        a0 = MFMA16(al0, Bf[0][0], a0);
        a1 = MFMA16(al0, Bf[1][0], a1);
        a2 = MFMA16(al0, Bf[2][0], a2);
        a3 = MFMA16(al0, Bf[3][0], a3);
        a0 = MFMA16(al1, Bf[0][1], a0);
        a1 = MFMA16(al1, Bf[1][1], a1);
        a2 = MFMA16(al1, Bf[2][1], a2);
        a3 = MFMA16(al1, Bf[3][1], a3);

        // ---- redistribute: upper half-wave takes r{2,3} from lane-32 ----
        float g00, g01, g10, g11, g20, g21, g30, g31;
        {
            float t02 = __shfl_xor(a0[2], 32), t03 = __shfl_xor(a0[3], 32);
            float t12 = __shfl_xor(a1[2], 32), t13 = __shfl_xor(a1[3], 32);
            float t22 = __shfl_xor(a2[2], 32), t23 = __shfl_xor(a2[3], 32);
            float t32 = __shfl_xor(a3[2], 32), t33 = __shfl_xor(a3[3], 32);
            g00 = lohalf ? a0[0] : t02;  g01 = lohalf ? a0[1] : t03;
            g10 = lohalf ? a1[0] : t12;  g11 = lohalf ? a1[1] : t13;
            g20 = lohalf ? a2[0] : t22;  g21 = lohalf ? a2[1] : t23;
            g30 = lohalf ? a3[0] : t32;  g31 = lohalf ? a3[1] : t33;
        }

        // ---- activations: 2 cells per lane ----
        const float xv0 = sh_x[t * SXP + m0];
        const float xv1 = sh_x[t * SXP + m0 + 1];
        {
            float gi = g00 + fmaf(xv0, wihv[0], biasv[0]);
            float gf = g10 + fmaf(xv0, wihv[1], biasv[1]);
            float gg = g20 + fmaf(xv0, wihv[2], biasv[2]);
            float go = g30 + fmaf(xv0, wihv[3], biasv[3]);
            float i_ = sigmoid_(gi), f_ = sigmoid_(gf);
            float g_ = tanh_(gg),   o_ = sigmoid_(go);
            cc0 = fmaf(f_, cc0, i_ * g_);
            float hv = o_ * tanh_(cc0);
            _Float16 hh = (_Float16)hv;
            wb[woff0]        = hh;
            wb[HALF + woff0] = (_Float16)(hv - (float)hh);
        }
        {
            float gi = g01 + fmaf(xv1, wihv[0], biasv[0]);
            float gf = g11 + fmaf(xv1, wihv[1], biasv[1]);
            float gg = g21 + fmaf(xv1, wihv[2], biasv[2]);
            float go = g31 + fmaf(xv1, wihv[3], biasv[3]);
            float i_ = sigmoid_(gi), f_ = sigmoid_(gf);
            float g_ = tanh_(gg),   o_ = sigmoid_(go);
            cc1 = fmaf(f_, cc1, i_ * g_);
            float hv = o_ * tanh_(cc1);
            _Float16 hh = (_Float16)hv;
            wb[woff1]        = hh;
            wb[HALF + woff1] = (_Float16)(hv - (float)hh);
        }
        __syncthreads();  // covers: writes->next reads AND reads->next writes
    }

    // ---- epilogue: final h is in buffer 0; out[b0+m] = h.w_out + b_out ----
    const float wo = w_out[L];
    #pragma unroll
    for (int p = 0; p < 2; ++p) {
        const int m = w + 4 * p;
        float hvf = (float)hbuf[m * HPAD + L] + (float)hbuf[HALF + m * HPAD + L];
        float v = hvf * wo;
        #pragma unroll
        for (int off = 32; off; off >>= 1) v += __shfl_down(v, off);
        if (L == 0) out[b0 + m] = v + b_out[0];
    }
}

extern "C" void kernel_launch(void* const* d_in, const int* in_sizes, int n_in,
                              void* d_out, int out_size, void* d_ws, size_t ws_size,
                              hipStream_t stream) {
    const float* x     = (const float*)d_in[0];
    const float* w_ih  = (const float*)d_in[1];
    const float* w_hh  = (const float*)d_in[2];
    const float* b_ih  = (const float*)d_in[3];
    const float* b_hh  = (const float*)d_in[4];
    const float* w_out = (const float*)d_in[5];
    const float* b_out = (const float*)d_in[6];
    float* out = (float*)d_out;

    lstm_mfma<<<4096 / MB, 256, 0, stream>>>(x, w_ih, w_hh, b_ih, b_hh,
                                             w_out, b_out, out);
}

// Round 4
// 347.555 us; speedup vs baseline: 1.2605x; 1.2605x over previous
//
#include <hip/hip_runtime.h>

// LSTM B=4096, T=512, I=1, H=64, O=1 (fp32 in/out).
// Round 4: MB=8, grid=512 (2 blocks/CU), hi/lo split PACKED INTO M:
//   A rows (16): row 2q = h_hi[batch q], row 2q+1 = h_lo[batch q]  (f16)
//   gates[q][n] = C[2q][n] + C[2q+1][n]  -> full M=16 per MFMA, 8 MFMA/step,
//   and D rows 4h0..4h0+3 sit in ONE lane's 4 acc regs = all 4 gates of
//   batches {2h0, 2h0+1}: gate = acc[r]+acc[r+1], ZERO shuffles.
// h stored in LDS interleaved-row f16 (stride HP=72: 16B-aligned, <=2-way
// bank alias on b128 reads = free), ping-pong buffers, ONE barrier/step.
// MFMA layouts (m89-verified): A[m=lane&15][k=(lane>>4)*8+i],
// B[k=(lane>>4)*8+i][n=lane&15], D[m=(lane>>4)*4+r][n=lane&15].

#define TT   512
#define MB   8
#define HP   72            // f16 row stride (144 B = 9*16: aligned, 2-way max)
#define BUFE (16 * HP)     // one ping-pong buffer: 16 rows
#define SXP  10            // sh_x row stride (floats): even (b64-aligned), 2-way

typedef _Float16 f16x8 __attribute__((ext_vector_type(8)));
typedef float    f32x4 __attribute__((ext_vector_type(4)));

#define MFMA16(a, b, c) __builtin_amdgcn_mfma_f32_16x16x32_f16((a), (b), (c), 0, 0, 0)

__device__ __forceinline__ float rcp_(float x) { return __builtin_amdgcn_rcpf(x); }
__device__ __forceinline__ float sigmoid_(float x) { return rcp_(1.0f + __expf(-x)); }
__device__ __forceinline__ float tanh_(float x) { return 1.0f - 2.0f * rcp_(1.0f + __expf(2.0f * x)); }

__device__ __forceinline__ f16x8 cvt8(const float4& u0, const float4& u1) {
    f16x8 r;
    r[0] = (_Float16)u0.x; r[1] = (_Float16)u0.y; r[2] = (_Float16)u0.z; r[3] = (_Float16)u0.w;
    r[4] = (_Float16)u1.x; r[5] = (_Float16)u1.y; r[6] = (_Float16)u1.z; r[7] = (_Float16)u1.w;
    return r;
}

__global__ __launch_bounds__(256, 2) void lstm_mfma(
    const float* __restrict__ x,      // [4096, 512]
    const float* __restrict__ w_ih,   // [256]
    const float* __restrict__ w_hh,   // [256, 64]
    const float* __restrict__ b_ih,   // [256]
    const float* __restrict__ b_hh,   // [256]
    const float* __restrict__ w_out,  // [64]
    const float* __restrict__ b_out,  // [1]
    float* __restrict__ out)          // [4096]
{
    __shared__ __align__(16) float    sh_x[TT * SXP];   // [t][m], 20 KB
    __shared__ __align__(16) _Float16 hbuf[2 * BUFE];   // 2 x 16 x HP, 4.6 KB

    const int tid = threadIdx.x;
    const int w   = tid >> 6;    // wave 0..3 (owns N-tiles {w, w+4, w+8, w+12})
    const int L   = tid & 63;
    const int l16 = L & 15;
    const int h0  = L >> 4;      // 0..3
    const int b0  = blockIdx.x * MB;
    const int j   = 16 * w + l16;  // hidden unit col owned by this lane

    // ---- stage x: sh_x[t*SXP + m] = x[b0+m][t] (coalesced; 2-way LDS) ----
    {
        const int q = tid >> 5;   // batch 0..7
        const int l = tid & 31;
        const float* xr = x + (size_t)(b0 + q) * TT;
        #pragma unroll
        for (int i = 0; i < TT / 32; ++i)
            sh_x[(l + 32 * i) * SXP + q] = xr[l + 32 * i];
    }
    // ---- zero both h buffers ----
    for (int i = tid; i < 2 * BUFE; i += 256) hbuf[i] = (_Float16)0.0f;

    // ---- preload W_hh fragments (fp16-rounded once) ----
    f16x8 Bf[4][2];
    float wihv[4], biasv[4];
    #pragma unroll
    for (int s = 0; s < 4; ++s) {
        const int n = 64 * s + j;
        #pragma unroll
        for (int kt = 0; kt < 2; ++kt) {
            const float* p = w_hh + n * 64 + kt * 32 + h0 * 8;
            float4 u0 = *(const float4*)p;
            float4 u1 = *(const float4*)(p + 4);
            Bf[s][kt] = cvt8(u0, u1);
        }
        wihv[s]  = w_ih[n];
        biasv[s] = b_ih[n] + b_hh[n];
    }

    // lane's A row m=l16: batch l16>>1, plane l16&1 (even=hi, odd=lo)
    const int aoff = l16 * HP + h0 * 8;   // f16 units; +32 for K-chunk 1
    // lane's cells: batches q0=2h0, q0+1; writes rows 4h0..4h0+3, col j
    const int xoff = 2 * h0;
    const int wr   = 4 * h0 * HP + j;

    float cc0 = 0.0f, cc1 = 0.0f;
    __syncthreads();

    auto step = [&](const _Float16* rb, _Float16* wb, int t) {
        // A fragments: one row, 2 K-chunks
        f16x8 a0 = *(const f16x8*)(rb + aoff);
        f16x8 a1 = *(const f16x8*)(rb + aoff + 32);

        const f32x4 z = {0.f, 0.f, 0.f, 0.f};
        f32x4 acc0 = MFMA16(a1, Bf[0][1], MFMA16(a0, Bf[0][0], z));
        f32x4 acc1 = MFMA16(a1, Bf[1][1], MFMA16(a0, Bf[1][0], z));
        f32x4 acc2 = MFMA16(a1, Bf[2][1], MFMA16(a0, Bf[2][0], z));
        f32x4 acc3 = MFMA16(a1, Bf[3][1], MFMA16(a0, Bf[3][0], z));

        const float2 xv = *(const float2*)(sh_x + t * SXP + xoff);

        // cell 0: batch q0 = 2h0   (gate = hi row + lo row = acc[0]+acc[1])
        {
            float gi = (acc0[0] + acc0[1]) + fmaf(xv.x, wihv[0], biasv[0]);
            float gf = (acc1[0] + acc1[1]) + fmaf(xv.x, wihv[1], biasv[1]);
            float gg = (acc2[0] + acc2[1]) + fmaf(xv.x, wihv[2], biasv[2]);
            float go = (acc3[0] + acc3[1]) + fmaf(xv.x, wihv[3], biasv[3]);
            float i_ = sigmoid_(gi), f_ = sigmoid_(gf);
            float g_ = tanh_(gg),   o_ = sigmoid_(go);
            cc0 = fmaf(f_, cc0, i_ * g_);
            float hv = o_ * tanh_(cc0);
            _Float16 hh = (_Float16)hv;
            wb[wr]      = hh;                          // row 4h0   (hi)
            wb[wr + HP] = (_Float16)(hv - (float)hh);  // row 4h0+1 (lo)
        }
        // cell 1: batch q0+1 (gate = acc[2]+acc[3])
        {
            float gi = (acc0[2] + acc0[3]) + fmaf(xv.y, wihv[0], biasv[0]);
            float gf = (acc1[2] + acc1[3]) + fmaf(xv.y, wihv[1], biasv[1]);
            float gg = (acc2[2] + acc2[3]) + fmaf(xv.y, wihv[2], biasv[2]);
            float go = (acc3[2] + acc3[3]) + fmaf(xv.y, wihv[3], biasv[3]);
            float i_ = sigmoid_(gi), f_ = sigmoid_(gf);
            float g_ = tanh_(gg),   o_ = sigmoid_(go);
            cc1 = fmaf(f_, cc1, i_ * g_);
            float hv = o_ * tanh_(cc1);
            _Float16 hh = (_Float16)hv;
            wb[wr + 2 * HP] = hh;                          // row 4h0+2 (hi)
            wb[wr + 3 * HP] = (_Float16)(hv - (float)hh);  // row 4h0+3 (lo)
        }
        __syncthreads();
    };

    for (int t = 0; t < TT; t += 2) {
        step(hbuf,        hbuf + BUFE, t);      // read buf0, write buf1
        step(hbuf + BUFE, hbuf,        t + 1);  // read buf1, write buf0
    }

    // ---- epilogue: final h in buf0; wave w reduces batches 2w, 2w+1 ----
    const float wo = w_out[L];
    #pragma unroll
    for (int p = 0; p < 2; ++p) {
        const int q = 2 * w + p;
        float hvf = (float)hbuf[(2 * q) * HP + L] + (float)hbuf[(2 * q + 1) * HP + L];
        float v = hvf * wo;
        #pragma unroll
        for (int off = 32; off; off >>= 1) v += __shfl_down(v, off);
        if (L == 0) out[b0 + q] = v + b_out[0];
    }
}

extern "C" void kernel_launch(void* const* d_in, const int* in_sizes, int n_in,
                              void* d_out, int out_size, void* d_ws, size_t ws_size,
                              hipStream_t stream) {
    const float* x     = (const float*)d_in[0];
    const float* w_ih  = (const float*)d_in[1];
    const float* w_hh  = (const float*)d_in[2];
    const float* b_ih  = (const float*)d_in[3];
    const float* b_hh  = (const float*)d_in[4];
    const float* w_out = (const float*)d_in[5];
    const float* b_out = (const float*)d_in[6];
    float* out = (float*)d_out;

    lstm_mfma<<<4096 / MB, 256, 0, stream>>>(x, w_ih, w_hh, b_ih, b_hh,
                                             w_out, b_out, out);
}